// Round 3
// baseline (472.287 us; speedup 1.0000x reference)
//
#include <hip/hip_runtime.h>
#include <math.h>

#define NN 4096
#define PP 10
#define DD 17
#define DIM 300
#define NPD (NN * PP * DD)

#define T_ENT (NN * PP * DD)      // 696,320 triples (n,p,k)
#define CNT_SZ 100352             // 98*1024 >= VOCAB-1 = 99,999 rows
#define NB_SCAN 98                // CNT_SZ / 1024
#define REP_CAP 65536             // repair list capacity (expected ~300 entries)
#define WS_NEEDED ((size_t)(CNT_SZ + 128 + 64 + T_ENT + REP_CAP) * 4)

// ---------------------------------------------------------------------------
// v4: row-sorted processing + boundary repair.
// R2 diagnosis: pipeline was CORRECT (output0 passed); output1 failed on a
// knife-edge triple whose reference logit is within ~1e-7 of the mask
// boundary -- a different FMA contraction in k_proc flipped its sign.
// Fixes:
//  (a) mask = (sigmoid >= 0.5) everywhere (reference float32 rounds
//      sigmoid(x) to exactly 0.5 for x in (-6e-8, 0]; sign-of-logit deviates),
//  (b) triples with |logit| < 1e-4 are re-processed by a verbatim copy of the
//      v0 wave kernel (the bit pattern that passed the prior session + R0/R1),
//      overwriting their whole wave's outputs. Far-from-boundary triples
//      cannot flip (bit drift ~1e-6 << 1e-4).
// ---------------------------------------------------------------------------

__global__ void k_zero(int* __restrict__ p, int n) {
    int i = blockIdx.x * blockDim.x + threadIdx.x;
    if (i < n) p[i] = 0;
}

__global__ void k_hist(const int* __restrict__ paths, int* __restrict__ cnt) {
    int t = blockIdx.x * blockDim.x + threadIdx.x;   // grid sized exactly T_ENT
    atomicAdd(&cnt[paths[t]], 1);
}

// In-place exclusive scan of each 1024-chunk of cnt; block totals to bsum.
__global__ __launch_bounds__(1024) void k_scan1(int* __restrict__ cnt, int* __restrict__ bsum) {
    __shared__ int s[1024];
    const int tid = threadIdx.x;
    const int i = blockIdx.x * 1024 + tid;
    const int v = cnt[i];
    s[tid] = v;
    __syncthreads();
    #pragma unroll
    for (int off = 1; off < 1024; off <<= 1) {
        int add = (tid >= off) ? s[tid - off] : 0;
        __syncthreads();
        s[tid] += add;
        __syncthreads();
    }
    cnt[i] = s[tid] - v;                       // exclusive
    if (tid == 1023) bsum[blockIdx.x] = s[1023];
}

__global__ void k_scan2(int* __restrict__ bsum) {   // scan NB_SCAN block totals
    if (threadIdx.x == 0) {
        int acc = 0;
        for (int b = 0; b < NB_SCAN; ++b) { int v = bsum[b]; bsum[b] = acc; acc += v; }
    }
}

__global__ __launch_bounds__(1024) void k_scan3(int* __restrict__ cnt, const int* __restrict__ bsum) {
    int i = blockIdx.x * 1024 + threadIdx.x;
    cnt[i] += bsum[blockIdx.x];
}

__global__ void k_scatter(const int* __restrict__ paths, int* __restrict__ cursor,
                          int* __restrict__ order) {
    int t = blockIdx.x * blockDim.x + threadIdx.x;   // grid sized exactly T_ENT
    int row = paths[t];
    int pos = atomicAdd(&cursor[row], 1);
    order[pos] = t;                                  // order[] sorted by row
}

// One half-wave (32 lanes) per sorted triple. Consecutive e => same/adjacent
// emb2 rows, so the emb2 read is effectively sequential; XCD remap gives each
// XCD a contiguous sorted span for L1/L2 reuse.
__global__ __launch_bounds__(256) void k_proc(
    const int* __restrict__ order,
    const int* __restrict__ word_idx,
    const int* __restrict__ paths,
    const int* __restrict__ labels,
    const float* __restrict__ emb1,
    const float* __restrict__ emb2,
    float* __restrict__ out,
    float* __restrict__ target,
    int* __restrict__ rep_cnt,
    int* __restrict__ rep_list)
{
    const int per = gridDim.x >> 3;                      // gridDim.x % 8 == 0
    const int vb  = (blockIdx.x & 7) * per + (blockIdx.x >> 3);
    const int e = vb * 8 + (int)(threadIdx.x >> 5);      // 8 half-waves/block
    const int j = (int)(threadIdx.x & 31);
    if (e >= T_ENT) return;

    const int t   = order[e];
    const int row = paths[t];
    const int n   = t / (PP * DD);

    const float4* p4 = (const float4*)(emb1 + (long long)word_idx[n] * DIM);
    const float4* r4 = (const float4*)(emb2 + (long long)row * DIM);

    const float4 p0 = p4[j],      r0 = r4[j];
    const float4 p1 = p4[j + 32], r1 = r4[j + 32];
    float acc = p0.x * r0.x + p0.y * r0.y + p0.z * r0.z + p0.w * r0.w
              + p1.x * r1.x + p1.y * r1.y + p1.z * r1.z + p1.w * r1.w;
    if (j < 11) {
        const float4 p2 = p4[j + 64], r2 = r4[j + 64];
        acc += p2.x * r2.x + p2.y * r2.y + p2.z * r2.z + p2.w * r2.w;
    }
    #pragma unroll
    for (int off = 16; off > 0; off >>= 1)
        acc += __shfl_xor(acc, off);

    if (j == 0) {
        const float o = 1.0f / (1.0f + expf(-acc));
        out[t] = o;
        const int mask = (o >= 0.5f) ? 1 : 0;            // reference semantics
        target[t] = (mask == labels[t]) ? 1.0f : 0.0f;
        if (fabsf(acc) < 1e-4f) {                        // knife-edge: queue wave repair
            int pos = atomicAdd(rep_cnt, 1);
            if (pos < REP_CAP) rep_list[pos] = t / DD;   // wave id = n*PP + p
        }
    }
}

// Repair: re-run the verbatim v0 wave kernel for listed waves, overwriting
// all 17 outputs of each with the empirically-validated bit pattern.
// Duplicates are idempotent (identical bits).
__global__ __launch_bounds__(256) void k_repair(
    const int* __restrict__ rep_cnt,
    const int* __restrict__ rep_list,
    const int* __restrict__ word_idx,
    const int* __restrict__ paths,
    const int* __restrict__ labels,
    const float* __restrict__ emb1,
    const float* __restrict__ emb2,
    float* __restrict__ out,
    float* __restrict__ target)
{
    const int nrep = min(*rep_cnt, REP_CAP);
    const int waves_per_grid = gridDim.x * (blockDim.x >> 6);
    const int lane = (int)(threadIdx.x & 63);
    for (int widx = blockIdx.x * (blockDim.x >> 6) + (int)(threadIdx.x >> 6);
         widx < nrep; widx += waves_per_grid) {
        const int wave = rep_list[widx];
        if ((unsigned)wave >= (unsigned)(NN * PP)) continue;
        const int n = wave / PP;
        const int j    = lane & 31;
        const int half = lane >> 5;

        const float4* p4 = (const float4*)(emb1 + (long long)word_idx[n] * DIM);
        const float4 pr0 = p4[j];
        const float4 pr1 = p4[j + 32];
        const float4 pr2 = (j < 11) ? p4[j + 64] : make_float4(0.f, 0.f, 0.f, 0.f);

        const long long base = (long long)wave * DD;
        const int my_path  = (lane < DD) ? paths[base + lane]  : 0;
        const int my_label = (lane < DD) ? labels[base + lane] : 0;

        float my_logit = 0.0f;
        #pragma unroll
        for (int i = 0; i < 9; ++i) {
            const int k = 2 * i + half;
            float acc = 0.0f;
            if (k < DD) {
                const int rrow = __shfl(my_path, k);
                const float4* r4 = (const float4*)(emb2 + (long long)rrow * DIM);
                const float4 a0 = r4[j];
                const float4 a1 = r4[j + 32];
                acc = pr0.x * a0.x + pr0.y * a0.y + pr0.z * a0.z + pr0.w * a0.w
                    + pr1.x * a1.x + pr1.y * a1.y + pr1.z * a1.z + pr1.w * a1.w;
                if (j < 11) {
                    const float4 a2 = r4[j + 64];
                    acc += pr2.x * a2.x + pr2.y * a2.y + pr2.z * a2.z + pr2.w * a2.w;
                }
            }
            #pragma unroll
            for (int off = 16; off > 0; off >>= 1)
                acc += __shfl_xor(acc, off);
            const float other = __shfl_xor(acc, 32);
            if (lane == 2 * i) my_logit = acc;
            if (2 * i + 1 < DD && lane == 2 * i + 1) my_logit = other;
        }

        if (lane < DD) {
            const float o = 1.0f / (1.0f + expf(-my_logit));
            out[base + lane] = o;
            const int mask = (o >= 0.5f) ? 1 : 0;
            target[base + lane] = (mask == my_label) ? 1.0f : 0.0f;
        }
    }
}

// ---------------------------------------------------------------------------
// Fallback (v0) single-kernel path, used only if workspace is too small.
// ---------------------------------------------------------------------------
__global__ __launch_bounds__(256) void hs_fwd_kernel(
    const int* __restrict__ word_idx, const int* __restrict__ paths,
    const int* __restrict__ labels, const float* __restrict__ emb1,
    const float* __restrict__ emb2, float* __restrict__ out, float* __restrict__ target)
{
    const int wave = (int)((blockIdx.x * blockDim.x + threadIdx.x) >> 6);
    const int lane = (int)(threadIdx.x & 63);
    if (wave >= NN * PP) return;
    const int n = wave / PP;
    const int j = lane & 31;
    const int half = lane >> 5;

    const float4* p4 = (const float4*)(emb1 + (long long)word_idx[n] * DIM);
    const float4 pr0 = p4[j];
    const float4 pr1 = p4[j + 32];
    const float4 pr2 = (j < 11) ? p4[j + 64] : make_float4(0.f, 0.f, 0.f, 0.f);

    const long long base = (long long)wave * DD;
    const int my_path  = (lane < DD) ? paths[base + lane]  : 0;
    const int my_label = (lane < DD) ? labels[base + lane] : 0;

    float my_logit = 0.0f;
    #pragma unroll
    for (int i = 0; i < 9; ++i) {
        const int k = 2 * i + half;
        float acc = 0.0f;
        if (k < DD) {
            const int row = __shfl(my_path, k);
            const float4* r4 = (const float4*)(emb2 + (long long)row * DIM);
            const float4 a0 = r4[j];
            const float4 a1 = r4[j + 32];
            acc = pr0.x * a0.x + pr0.y * a0.y + pr0.z * a0.z + pr0.w * a0.w
                + pr1.x * a1.x + pr1.y * a1.y + pr1.z * a1.z + pr1.w * a1.w;
            if (j < 11) {
                const float4 a2 = r4[j + 64];
                acc += pr2.x * a2.x + pr2.y * a2.y + pr2.z * a2.z + pr2.w * a2.w;
            }
        }
        #pragma unroll
        for (int off = 16; off > 0; off >>= 1)
            acc += __shfl_xor(acc, off);
        const float other = __shfl_xor(acc, 32);
        if (lane == 2 * i) my_logit = acc;
        if (2 * i + 1 < DD && lane == 2 * i + 1) my_logit = other;
    }

    if (lane < DD) {
        const float o = 1.0f / (1.0f + expf(-my_logit));
        out[base + lane] = o;
        const int mask = (o >= 0.5f) ? 1 : 0;
        target[base + lane] = (mask == my_label) ? 1.0f : 0.0f;
    }
}

extern "C" void kernel_launch(void* const* d_in, const int* in_sizes, int n_in,
                              void* d_out, int out_size, void* d_ws, size_t ws_size,
                              hipStream_t stream) {
    const int*   word_idx = (const int*)d_in[0];
    const int*   paths    = (const int*)d_in[1];
    const int*   labels   = (const int*)d_in[2];
    const float* emb1     = (const float*)d_in[3];
    const float* emb2     = (const float*)d_in[4];

    float* out    = (float*)d_out;
    float* target = (float*)d_out + NPD;

    if (ws_size < WS_NEEDED || d_ws == nullptr) {
        const int total_waves = NN * PP;
        const int blocks = (total_waves * 64 + 255) / 256;
        hs_fwd_kernel<<<blocks, 256, 0, stream>>>(word_idx, paths, labels, emb1, emb2, out, target);
        return;
    }

    int* cursor   = (int*)d_ws;               // [CNT_SZ]  counts -> offsets -> cursors
    int* bsum     = cursor + CNT_SZ;          // [128]
    int* rep_cnt  = bsum + 128;               // [64] (slot 0 used)
    int* order    = rep_cnt + 64;             // [T_ENT]
    int* rep_list = order + T_ENT;            // [REP_CAP]

    // 1. zero counters + bsum + rep_cnt
    {
        const int n = CNT_SZ + 128 + 64;
        k_zero<<<(n + 255) / 256, 256, 0, stream>>>(cursor, n);
    }
    // 2. histogram of row ids
    k_hist<<<T_ENT / 256, 256, 0, stream>>>(paths, cursor);
    // 3. exclusive scan (3 small kernels)
    k_scan1<<<NB_SCAN, 1024, 0, stream>>>(cursor, bsum);
    k_scan2<<<1, 64, 0, stream>>>(bsum);
    k_scan3<<<NB_SCAN, 1024, 0, stream>>>(cursor, bsum);
    // 4. scatter triple indices into row-sorted order
    k_scatter<<<T_ENT / 256, 256, 0, stream>>>(paths, cursor, order);
    // 5. process sorted triples (8 half-waves per 256-thread block)
    k_proc<<<T_ENT / 8, 256, 0, stream>>>(order, word_idx, paths, labels,
                                          emb1, emb2, out, target, rep_cnt, rep_list);
    // 6. boundary repair with verbatim v0 arithmetic
    k_repair<<<64, 256, 0, stream>>>(rep_cnt, rep_list, word_idx, paths, labels,
                                     emb1, emb2, out, target);
}